// Round 2
// baseline (864.796 us; speedup 1.0000x reference)
//
#include <hip/hip_runtime.h>
#include <hip/hip_bf16.h>

// OnlineDenoisingAutoencoder: LSTM(B=2048, T=2048, in=1, proj=16, H=32)
// Strategy: 1 wave per batch element (2048 waves = 2 waves/SIMD on 1024 SIMDs).
// Lane l owns W_hh rows l (i/f) and 64+l (g/o) in registers (64 VGPRs of weights).
// h[32] gathered per step via broadcast ds_read_b128 from per-wave LDS slot.
// Input pipeline collapsed to gate = x*A[g] + C[g] since INPUT_DIM == 1.
// Output projection fused (shuffle reduce). No __syncthreads anywhere.
// Output dtype: float32 (reference is all-fp32; threshold is 2% of max|ref|).

#define BB 2048
#define TT 2048
#define HH 32

__device__ __forceinline__ float gate_eval(float x, float m, float a, float b) {
    // a * (1 / (1 + 2^(m*x))) + b  ; sigmoid: m=-log2e,a=1,b=0 ; tanh: m=-2log2e,a=2,b=-1
    float e = __builtin_amdgcn_exp2f(x * m);
    float r = __builtin_amdgcn_rcpf(1.0f + e);
    return fmaf(a, r, b);
}

__global__ __launch_bounds__(256) void lstm_fused_kernel(
    const float* __restrict__ x_seq,  // [B,T,1]
    const float* __restrict__ Wp,     // [16,1]
    const float* __restrict__ bp,     // [16]
    const float* __restrict__ W_ih,   // [128,16]
    const float* __restrict__ W_hh,   // [128,32]
    const float* __restrict__ b_ih,   // [128]
    const float* __restrict__ b_hh,   // [128]
    const float* __restrict__ Wo,     // [1,32]
    const float* __restrict__ bo,     // [1]
    float* __restrict__ out)          // [B,T,1] fp32
{
    const int tid  = threadIdx.x;
    const int wave = tid >> 6;
    const int lane = tid & 63;
    const int half = lane >> 5;      // 0: rows l (i), 64+l (g); 1: rows l (f), 64+l (o)
    const int j    = lane & 31;      // hidden index this lane owns
    const int b    = blockIdx.x * 4 + wave;

    const int rA = lane;             // 0..63  : i_j (l<32) or f_j (l>=32)
    const int rB = 64 + lane;        // 64..127: g_j (l<32) or o_j (l>=32)

    // ---- W_hh rows into registers (one-time) ----
    float wA[HH], wB[HH];
    {
        const float4* pa = (const float4*)(W_hh + rA * HH);
        const float4* pb = (const float4*)(W_hh + rB * HH);
#pragma unroll
        for (int k = 0; k < HH / 4; ++k) {
            float4 va = pa[k], vb = pb[k];
            wA[4*k+0] = va.x; wA[4*k+1] = va.y; wA[4*k+2] = va.z; wA[4*k+3] = va.w;
            wB[4*k+0] = vb.x; wB[4*k+1] = vb.y; wB[4*k+2] = vb.z; wB[4*k+3] = vb.w;
        }
    }

    // ---- collapse input pipeline: gate_g(x) = x*a + c ----
    float aA = 0.f, cA = 0.f, aB = 0.f, cB = 0.f;
#pragma unroll
    for (int p = 0; p < 16; ++p) {
        float wia = W_ih[rA * 16 + p], wib = W_ih[rB * 16 + p];
        aA = fmaf(wia, Wp[p], aA);
        cA = fmaf(wia, bp[p], cA);
        aB = fmaf(wib, Wp[p], aB);
        cB = fmaf(wib, bp[p], cB);
    }
    cA += b_ih[rA] + b_hh[rA];
    cB += b_ih[rB] + b_hh[rB];

    const float LOG2E = 1.44269504088896340736f;
    // gate A (i or f): sigmoid for everyone. gate B: tanh (g) on half0, sigmoid (o) on half1.
    const float mB  = half ? -LOG2E : -2.0f * LOG2E;
    const float aBc = half ? 1.0f : 2.0f;
    const float bBc = half ? 0.0f : -1.0f;

    const float woj = Wo[j];
    const float bo0 = bo[0];

    // per-wave h buffer; half1 writes a shadow copy (never read) to stay branchless.
    __shared__ float hsh[4][2][40];
    hsh[wave][half][j] = 0.0f;

    float c = 0.0f;
    const float* xp = x_seq + (size_t)b * TT;
    float* op = out + (size_t)b * TT;

    for (int t = 0; t < TT; t += 4) {
        float4 x4 = *(const float4*)(xp + t);
        float outv[4];
#pragma unroll
        for (int u = 0; u < 4; ++u) {
            float xv = (u == 0) ? x4.x : (u == 1) ? x4.y : (u == 2) ? x4.z : x4.w;

            // gather previous h (broadcast read, conflict-free)
            float hr[HH];
            {
                const float4* hp = (const float4*)(&hsh[wave][0][0]);
#pragma unroll
                for (int k = 0; k < HH / 4; ++k) {
                    float4 v = hp[k];
                    hr[4*k+0] = v.x; hr[4*k+1] = v.y; hr[4*k+2] = v.z; hr[4*k+3] = v.w;
                }
            }

            // two 32-long dots, 2 accumulators each for ILP
            float sA0 = cA, sA1 = xv * aA;
            float sB0 = cB, sB1 = xv * aB;
#pragma unroll
            for (int k = 0; k < HH; k += 2) {
                sA0 = fmaf(wA[k],     hr[k],     sA0);
                sA1 = fmaf(wA[k + 1], hr[k + 1], sA1);
                sB0 = fmaf(wB[k],     hr[k],     sB0);
                sB1 = fmaf(wB[k + 1], hr[k + 1], sB1);
            }
            float gA = sA0 + sA1;
            float gB = sB0 + sB1;

            float vA = gate_eval(gA, -LOG2E, 1.0f, 0.0f); // sigmoid(i or f)
            float vB = gate_eval(gB, mB, aBc, bBc);       // tanh(g) or sigmoid(o)

            // exchange across halves so both compute the cell update
            float pA = __shfl_xor(vA, 32, 64);
            float pB = __shfl_xor(vB, 32, 64);
            float iv = half ? pA : vA;
            float fv = half ? vA : pA;
            float gv = half ? pB : vB;
            float ov = half ? vB : pB;

            c = fmaf(fv, c, iv * gv);
            float th = gate_eval(c, -2.0f * LOG2E, 2.0f, -1.0f); // tanh(c)
            float h = ov * th;

            hsh[wave][half][j] = h;

            // fused output projection: dot(Wo, h) via shuffle reduce (width 32)
            float po = woj * h;
#pragma unroll
            for (int m = 16; m >= 1; m >>= 1)
                po += __shfl_xor(po, m, 32);
            outv[u] = po + bo0;
        }
        if (lane == 0) {
            *(float4*)(op + t) = make_float4(outv[0], outv[1], outv[2], outv[3]);
        }
    }
}

extern "C" void kernel_launch(void* const* d_in, const int* in_sizes, int n_in,
                              void* d_out, int out_size, void* d_ws, size_t ws_size,
                              hipStream_t stream) {
    const float* x_seq = (const float*)d_in[0];
    const float* Wp    = (const float*)d_in[1];
    const float* bp    = (const float*)d_in[2];
    const float* W_ih  = (const float*)d_in[3];
    const float* W_hh  = (const float*)d_in[4];
    const float* b_ih  = (const float*)d_in[5];
    const float* b_hh  = (const float*)d_in[6];
    const float* Wo    = (const float*)d_in[7];
    const float* bo    = (const float*)d_in[8];
    float* out = (float*)d_out;

    dim3 grid(BB / 4);   // 4 waves per block, 1 batch element per wave
    dim3 block(256);
    lstm_fused_kernel<<<grid, block, 0, stream>>>(
        x_seq, Wp, bp, W_ih, W_hh, b_ih, b_hh, Wo, bo, out);
}